// Round 9
// baseline (657.349 us; speedup 1.0000x reference)
//
#include <hip/hip_runtime.h>

#define BATCH   4096
#define IN_DIM  1024
#define OUT_DIM 1024
#define NB      8                 // DEGREE + 1
#define NBK     7                 // basis funcs in the GEMM (d=1..7; d=0 is a bias)
#define KD2     (IN_DIM * NBK)    // 7168

typedef __bf16 bf16x8 __attribute__((ext_vector_type(8)));
typedef float  f32x4  __attribute__((ext_vector_type(4)));
typedef unsigned short us8 __attribute__((ext_vector_type(8)));

__device__ __forceinline__ unsigned short f2bf(float f) {
    unsigned int u = __float_as_uint(f);
    u += 0x7fffu + ((u >> 16) & 1u);   // round-to-nearest-even
    return (unsigned short)(u >> 16);
}

// fast tanh: 1 - 2/(e^{2x}+1) via v_exp_f32 + v_rcp_f32; exact limits at +-inf.
__device__ __forceinline__ float fast_tanh(float x) {
    const float LOG2E_X2 = 2.8853900817779268f;   // 2*log2(e)
    float e = __builtin_amdgcn_exp2f(x * LOG2E_X2);
    return 1.0f - 2.0f * __builtin_amdgcn_rcpf(e + 1.0f);
}

__device__ __forceinline__ void ld_lds16(const unsigned short* g, unsigned short* l) {
    __builtin_amdgcn_global_load_lds(
        (const __attribute__((address_space(1))) void*)g,
        (__attribute__((address_space(3))) void*)l, 16, 0, 0);
}

// ---------------------------------------------------------------------------
// Kernel 1 (fused, 3 block roles in one dispatch, 256 threads):
//  [0, 2048):        basis prep, 8 x-values/thread, LDS-free
//  [2048, 2560):     coeffs repack + exact fp32 bias partials
//  [2560, 3584):     zero C
// ---------------------------------------------------------------------------
#define PREP_BLOCKS   (BATCH * IN_DIM / (256 * 8))  // 2048
#define REPACK_BLOCKS 512
#define ZERO_BLOCKS   (BATCH * OUT_DIM / 4096)      // 1024
#define TI 32
#define TO 64
#define RSTR 232    // LDS row stride (ushorts) per o: 224 data + 8 pad

__global__ __launch_bounds__(256) void prep_and_repack(
    const float* __restrict__ x, const float* __restrict__ ap,
    const float* __restrict__ qp, const float* __restrict__ coeffs,
    unsigned short* __restrict__ Aw, unsigned short* __restrict__ Bt,
    float* __restrict__ bias_part,   // [32][OUT_DIM]
    float* __restrict__ C) {
    __shared__ __align__(16) unsigned short lt[TO * RSTR + 512];  // 30 KB (repack only)
    const int tid = threadIdx.x;

    if (blockIdx.x < PREP_BLOCKS) {
        const size_t idx = (size_t)blockIdx.x * 256 + tid;   // group of 8
        const float a = ap[0], q = qp[0];
        float xv[8];
        *(f32x4*)(xv)     = *(const f32x4*)(x + idx * 8);
        *(f32x4*)(xv + 4) = *(const f32x4*)(x + idx * 8 + 4);
        unsigned short tmp[56];
#pragma unroll
        for (int ii = 0; ii < 8; ++ii) {
            const float xt = fast_tanh(xv[ii]);
            float p[NB];
            p[0] = 1.0f;
            p[1] = xt - a;
            float qn = q, qn1 = 1.0f;
#pragma unroll
            for (int n = 2; n < NB; ++n) {
                qn *= q; qn1 *= q;
                p[n] = (xt - (a + qn)) * p[n - 1] - a * qn1 * p[n - 2];
            }
#pragma unroll
            for (int d = 1; d < NB; ++d) tmp[ii * 7 + d - 1] = f2bf(p[d]);
        }
        unsigned short* dst = Aw + idx * 56;
#pragma unroll
        for (int j = 0; j < 7; ++j)
            *(us8*)(dst + j * 8) = *(const us8*)(tmp + j * 8);
        return;
    }

    const int bid = blockIdx.x - PREP_BLOCKS;
    if (bid < REPACK_BLOCKS) {
        const int g  = bid & 31;
        const int i0 = g * TI;
        const int o0 = (bid >> 5) * TO;
        const int o_local = tid & 63;
        float bpart = 0.f;
#pragma unroll
        for (int pass = 0; pass < 8; ++pass) {
            const int i_local = pass * 4 + (tid >> 6);
            const float* src = coeffs +
                ((size_t)(i0 + i_local) * OUT_DIM + (o0 + o_local)) * NB;
            float4 v0 = *(const float4*)src;
            float4 v1 = *(const float4*)(src + 4);
            bpart += v0.x;                       // d = 0 -> exact fp32 bias
            unsigned short* dst = lt + o_local * RSTR + i_local * 7;
            dst[0] = f2bf(v0.y); dst[1] = f2bf(v0.z); dst[2] = f2bf(v0.w);
            dst[3] = f2bf(v1.x); dst[4] = f2bf(v1.y); dst[5] = f2bf(v1.z);
            dst[6] = f2bf(v1.w);
        }
        float* sb = (float*)(lt + TO * RSTR);    // 256 floats
        sb[(tid >> 6) * 64 + o_local] = bpart;
        __syncthreads();
        if (tid < 64)
            bias_part[(size_t)g * OUT_DIM + o0 + tid] =
                sb[tid] + sb[64 + tid] + sb[128 + tid] + sb[192 + tid];
#pragma unroll
        for (int pass = 0; pass < 7; ++pass) {
            const int o = tid >> 2;
            const int c = (tid & 3) + 4 * pass;  // 28 chunks x 16 B
            us8 v = *(const us8*)(lt + o * RSTR + c * 8);
            *(us8*)(Bt + (size_t)(o0 + o) * KD2 + i0 * 7 + c * 8) = v;
        }
        return;
    }

    const int z = bid - REPACK_BLOCKS;
    float* dst = C + (size_t)z * 4096 + tid * 4;
    const f32x4 zero = {0.f, 0.f, 0.f, 0.f};
#pragma unroll
    for (int j = 0; j < 4; ++j) *(f32x4*)(dst + j * 1024) = zero;
}

// ---------------------------------------------------------------------------
// Kernel 2: GEMM  C[M,N] += A[M,KD2] * Bt[N,KD2]^T  (bf16 -> fp32, split-K x4,
// atomicAdd into zeroed C; ch==0 blocks also add the exact d=0 bias).
// *** R5 configuration restored — best measured (gemm 95.5 us / 645 TF). ***
// BM=BN=128, BK=64, 256 thr (2x2 waves, wave tile 64x64), grid 1024 ->
// 4 blocks/CU. Plain 2-barrier K-loop (R6 bigger-block, R7 dbuf, R8
// 2-wave-block variants all regressed: the m97-family plateau).
// XCD mapping: bidx&7 = m-tile mod 8; all 4 K-chunks of a tile share an XCD
// (atomics resolve in one L2).
// LDS swizzle: row r stores logical k-chunk s at slot s ^ (r & 7) -> every
// ds_read_b128 covers banks uniformly (0 conflicts, R4-R5 measured).
// Epilogue: mt order rotated by ch so the 4 chunks of a tile start their
// atomic bursts on disjoint row quarters (less L2 RMW serialization).
// ---------------------------------------------------------------------------
#define BM 128
#define BN 128
#define BK 64
#define KSPLIT 4
#define KCH (KD2 / KSPLIT)   // 1792 -> 28 iters of BK=64

__global__ __launch_bounds__(256, 4) void gemm_kernel(
    const unsigned short* __restrict__ A,    // bf16 bits [BATCH][KD2]
    const unsigned short* __restrict__ Bt,   // bf16 bits [OUT_DIM][KD2]
    const float* __restrict__ bias_part,     // [32][OUT_DIM]
    float* __restrict__ C) {                 // [BATCH][OUT_DIM], pre-zeroed
    __shared__ __align__(16) unsigned short lA[BM * BK];  // 16 KB
    __shared__ __align__(16) unsigned short lB[BN * BK];  // 16 KB

    const int tid  = threadIdx.x;
    const int bidx = blockIdx.x;
    const int m0 = (((bidx >> 3) & 3) * 8 + (bidx & 7)) * BM;  // low3 -> XCD
    const int n0 = ((bidx >> 5) & 7) * BN;
    const int ch = bidx >> 8;
    const size_t kb = (size_t)ch * KCH;

    const int lane  = tid & 63;
    const int wid   = tid >> 6;
    const int wm    = (wid & 1) * 64;
    const int wn    = (wid >> 1) * 64;
    const int row16 = lane & 15;
    const int quad  = lane >> 4;

    // ds_read element offsets for kk=0; kk=1 is ^32 elems (slot ^4).
    int aOff[4], bOff[4];
#pragma unroll
    for (int mt = 0; mt < 4; ++mt) {
        int r = wm + mt * 16 + row16;
        aOff[mt] = r * BK + ((quad ^ (r & 7)) * 8);
    }
#pragma unroll
    for (int nt = 0; nt < 4; ++nt) {
        int c = wn + nt * 16 + row16;
        bOff[nt] = c * BK + ((quad ^ (c & 7)) * 8);
    }

    // Staging: tile = 1024 x 16B chunks; thread t -> chunks t + 256*j.
    // Phys chunk c: row r = c>>3, slot s = c&7, global k-chunk = s ^ (r&7).
    // c+256 -> r+32 (r&7 unchanged -> same swizzle term), +32*KD2 elems.
    const int r0 = tid >> 3, s0 = tid & 7;
    const unsigned short* gA0 = A  + (size_t)(m0 + r0) * KD2 + kb + ((s0 ^ (r0 & 7)) * 8);
    const unsigned short* gB0 = Bt + (size_t)(n0 + r0) * KD2 + kb + ((s0 ^ (r0 & 7)) * 8);
    unsigned short* dA = lA + tid * 8;
    unsigned short* dB = lB + tid * 8;

    f32x4 acc[4][4] = {};

    for (int k0 = 0; k0 < KCH; k0 += BK) {
#pragma unroll
        for (int j = 0; j < 4; ++j)
            ld_lds16(gA0 + k0 + (size_t)j * 32 * KD2, dA + j * 2048);
#pragma unroll
        for (int j = 0; j < 4; ++j)
            ld_lds16(gB0 + k0 + (size_t)j * 32 * KD2, dB + j * 2048);
        __syncthreads();

#pragma unroll
        for (int kk = 0; kk < 2; ++kk) {
            const int xo = kk * 32;
            bf16x8 aF[4], bF[4];
#pragma unroll
            for (int mt = 0; mt < 4; ++mt) aF[mt] = *(const bf16x8*)(lA + (aOff[mt] ^ xo));
#pragma unroll
            for (int nt = 0; nt < 4; ++nt) bF[nt] = *(const bf16x8*)(lB + (bOff[nt] ^ xo));
#pragma unroll
            for (int mt = 0; mt < 4; ++mt)
#pragma unroll
                for (int nt = 0; nt < 4; ++nt)
                    acc[mt][nt] = __builtin_amdgcn_mfma_f32_16x16x32_bf16(
                        aF[mt], bF[nt], acc[mt][nt], 0, 0, 0);
        }
        __syncthreads();
    }

    // ch==0 blocks fold in the exact d=0 bias.
    if (ch == 0) {
        float* sb = (float*)lA;   // safe: loop ended with __syncthreads
        if (tid < BN) {
            float s = 0.f;
#pragma unroll
            for (int g = 0; g < 32; ++g) s += bias_part[(size_t)g * OUT_DIM + n0 + tid];
            sb[tid] = s;
        }
        __syncthreads();
    }
    const float* sb = (const float*)lA;

    // C/D layout (m89-verified): col = lane&15, row = quad*4 + reg.
    // mt order rotated by ch: disjoint address quarters across chunk bursts.
#pragma unroll
    for (int mti = 0; mti < 4; ++mti) {
        const int mt = (mti + ch) & 3;
        const int rbase = m0 + wm + mt * 16 + quad * 4;
#pragma unroll
        for (int nt = 0; nt < 4; ++nt) {
            const int col = n0 + wn + nt * 16 + row16;
            const float bv = (ch == 0) ? sb[wn + nt * 16 + row16] : 0.f;
#pragma unroll
            for (int r = 0; r < 4; ++r)
                atomicAdd(&C[(size_t)(rbase + r) * OUT_DIM + col], acc[mt][nt][r] + bv);
        }
    }
}

// ---------------------------------------------------------------------------
// Fallback (only if ws too small): fp32, block per batch row, basis in LDS.
// ---------------------------------------------------------------------------
__global__ __launch_bounds__(256) void fallback_kernel(
    const float* __restrict__ x, const float* __restrict__ ap,
    const float* __restrict__ qp, const float* __restrict__ coeffs,
    float* __restrict__ out) {
    __shared__ float sb[IN_DIM][NB];   // 32 KB
    const int b = blockIdx.x;
    const float a = ap[0], q = qp[0];
    for (int i = threadIdx.x; i < IN_DIM; i += 256) {
        float xt = fast_tanh(x[(size_t)b * IN_DIM + i]);
        float p0 = 1.0f, p1 = xt - a;
        sb[i][0] = p0; sb[i][1] = p1;
        float qn = q, qn1 = 1.0f;
#pragma unroll
        for (int n = 2; n < NB; ++n) {
            qn *= q; qn1 *= q;
            float p2 = (xt - (a + qn)) * p1 - a * qn1 * p0;
            sb[i][n] = p2;
            p0 = p1; p1 = p2;
        }
    }
    __syncthreads();
    float acc[4] = {0.f, 0.f, 0.f, 0.f};
    for (int i = 0; i < IN_DIM; ++i) {
        float bb[NB];
#pragma unroll
        for (int d = 0; d < NB; ++d) bb[d] = sb[i][d];
#pragma unroll
        for (int j = 0; j < 4; ++j) {
            int o = threadIdx.x + j * 256;
            const float* cf = coeffs + ((size_t)i * OUT_DIM + o) * NB;
            float s = 0.f;
#pragma unroll
            for (int d = 0; d < NB; ++d) s += bb[d] * cf[d];
            acc[j] += s;
        }
    }
#pragma unroll
    for (int j = 0; j < 4; ++j)
        out[(size_t)b * OUT_DIM + threadIdx.x + j * 256] = acc[j];
}

// ---------------------------------------------------------------------------
extern "C" void kernel_launch(void* const* d_in, const int* in_sizes, int n_in,
                              void* d_out, int out_size, void* d_ws, size_t ws_size,
                              hipStream_t stream) {
    const float* x      = (const float*)d_in[0];
    const float* a      = (const float*)d_in[1];
    const float* q      = (const float*)d_in[2];
    const float* coeffs = (const float*)d_in[3];
    float* out = (float*)d_out;

    const size_t needA = (size_t)BATCH * KD2 * sizeof(unsigned short);   // 56 MB
    const size_t needB = (size_t)OUT_DIM * KD2 * sizeof(unsigned short); // 14 MB
    const size_t needBias = 32 * (size_t)OUT_DIM * sizeof(float);        // 128 KB

    if (ws_size >= needA + needB + needBias) {
        unsigned short* Aw = (unsigned short*)d_ws;
        unsigned short* Bt = Aw + (size_t)BATCH * KD2;
        float* bias_part = (float*)((char*)d_ws + needA + needB);
        prep_and_repack<<<PREP_BLOCKS + REPACK_BLOCKS + ZERO_BLOCKS, 256, 0, stream>>>(
            x, a, q, coeffs, Aw, Bt, bias_part, out);
        gemm_kernel<<<(BATCH / BM) * (OUT_DIM / BN) * KSPLIT, 256, 0, stream>>>(
            Aw, Bt, bias_part, out);
    } else {
        fallback_kernel<<<BATCH, 256, 0, stream>>>(x, a, q, coeffs, out);
    }
}

// Round 10
// 208.461 us; speedup vs baseline: 3.1533x; 3.1533x over previous
//
#include <hip/hip_runtime.h>

#define BATCH   4096
#define IN_DIM  1024
#define OUT_DIM 1024
#define NB      8                 // DEGREE + 1
#define NBK     7                 // basis funcs in the GEMM (d=1..7; d=0 is a bias)
#define KD2     (IN_DIM * NBK)    // 7168

typedef __bf16 bf16x8 __attribute__((ext_vector_type(8)));
typedef float  f32x4  __attribute__((ext_vector_type(4)));
typedef unsigned short us8 __attribute__((ext_vector_type(8)));

__device__ __forceinline__ unsigned short f2bf(float f) {
    unsigned int u = __float_as_uint(f);
    u += 0x7fffu + ((u >> 16) & 1u);   // round-to-nearest-even
    return (unsigned short)(u >> 16);
}

// fast tanh: 1 - 2/(e^{2x}+1) via v_exp_f32 + v_rcp_f32; exact limits at +-inf.
__device__ __forceinline__ float fast_tanh(float x) {
    const float LOG2E_X2 = 2.8853900817779268f;   // 2*log2(e)
    float e = __builtin_amdgcn_exp2f(x * LOG2E_X2);
    return 1.0f - 2.0f * __builtin_amdgcn_rcpf(e + 1.0f);
}

__device__ __forceinline__ void ld_lds16(const unsigned short* g, unsigned short* l) {
    __builtin_amdgcn_global_load_lds(
        (const __attribute__((address_space(1))) void*)g,
        (__attribute__((address_space(3))) void*)l, 16, 0, 0);
}

// ---------------------------------------------------------------------------
// Kernel 1 (fused, 3 block roles in one dispatch, 256 threads):
//  [0, 2048):        basis prep, 8 x-values/thread, LDS-free
//  [2048, 2560):     coeffs repack + exact fp32 bias partials
//  [2560, 3584):     zero C
// ---------------------------------------------------------------------------
#define PREP_BLOCKS   (BATCH * IN_DIM / (256 * 8))  // 2048
#define REPACK_BLOCKS 512
#define ZERO_BLOCKS   (BATCH * OUT_DIM / 4096)      // 1024
#define TI 32
#define TO 64
#define RSTR 232    // LDS row stride (ushorts) per o: 224 data + 8 pad

__global__ __launch_bounds__(256) void prep_and_repack(
    const float* __restrict__ x, const float* __restrict__ ap,
    const float* __restrict__ qp, const float* __restrict__ coeffs,
    unsigned short* __restrict__ Aw, unsigned short* __restrict__ Bt,
    float* __restrict__ bias_part,   // [32][OUT_DIM]
    float* __restrict__ C) {
    __shared__ __align__(16) unsigned short lt[TO * RSTR + 512];  // 30 KB (repack only)
    const int tid = threadIdx.x;

    if (blockIdx.x < PREP_BLOCKS) {
        const size_t idx = (size_t)blockIdx.x * 256 + tid;   // group of 8
        const float a = ap[0], q = qp[0];
        float xv[8];
        *(f32x4*)(xv)     = *(const f32x4*)(x + idx * 8);
        *(f32x4*)(xv + 4) = *(const f32x4*)(x + idx * 8 + 4);
        unsigned short tmp[56];
#pragma unroll
        for (int ii = 0; ii < 8; ++ii) {
            const float xt = fast_tanh(xv[ii]);
            float p[NB];
            p[0] = 1.0f;
            p[1] = xt - a;
            float qn = q, qn1 = 1.0f;
#pragma unroll
            for (int n = 2; n < NB; ++n) {
                qn *= q; qn1 *= q;
                p[n] = (xt - (a + qn)) * p[n - 1] - a * qn1 * p[n - 2];
            }
#pragma unroll
            for (int d = 1; d < NB; ++d) tmp[ii * 7 + d - 1] = f2bf(p[d]);
        }
        unsigned short* dst = Aw + idx * 56;
#pragma unroll
        for (int j = 0; j < 7; ++j)
            *(us8*)(dst + j * 8) = *(const us8*)(tmp + j * 8);
        return;
    }

    const int bid = blockIdx.x - PREP_BLOCKS;
    if (bid < REPACK_BLOCKS) {
        const int g  = bid & 31;
        const int i0 = g * TI;
        const int o0 = (bid >> 5) * TO;
        const int o_local = tid & 63;
        float bpart = 0.f;
#pragma unroll
        for (int pass = 0; pass < 8; ++pass) {
            const int i_local = pass * 4 + (tid >> 6);
            const float* src = coeffs +
                ((size_t)(i0 + i_local) * OUT_DIM + (o0 + o_local)) * NB;
            float4 v0 = *(const float4*)src;
            float4 v1 = *(const float4*)(src + 4);
            bpart += v0.x;                       // d = 0 -> exact fp32 bias
            unsigned short* dst = lt + o_local * RSTR + i_local * 7;
            dst[0] = f2bf(v0.y); dst[1] = f2bf(v0.z); dst[2] = f2bf(v0.w);
            dst[3] = f2bf(v1.x); dst[4] = f2bf(v1.y); dst[5] = f2bf(v1.z);
            dst[6] = f2bf(v1.w);
        }
        float* sb = (float*)(lt + TO * RSTR);    // 256 floats
        sb[(tid >> 6) * 64 + o_local] = bpart;
        __syncthreads();
        if (tid < 64)
            bias_part[(size_t)g * OUT_DIM + o0 + tid] =
                sb[tid] + sb[64 + tid] + sb[128 + tid] + sb[192 + tid];
#pragma unroll
        for (int pass = 0; pass < 7; ++pass) {
            const int o = tid >> 2;
            const int c = (tid & 3) + 4 * pass;  // 28 chunks x 16 B
            us8 v = *(const us8*)(lt + o * RSTR + c * 8);
            *(us8*)(Bt + (size_t)(o0 + o) * KD2 + i0 * 7 + c * 8) = v;
        }
        return;
    }

    const int z = bid - REPACK_BLOCKS;
    float* dst = C + (size_t)z * 4096 + tid * 4;
    const f32x4 zero = {0.f, 0.f, 0.f, 0.f};
#pragma unroll
    for (int j = 0; j < 4; ++j) *(f32x4*)(dst + j * 1024) = zero;
}

// ---------------------------------------------------------------------------
// Kernel 2: GEMM  C[M,N] += A[M,KD2] * Bt[N,KD2]^T  (bf16 -> fp32, split-K x4,
// atomicAdd into zeroed C; ch==0 blocks also add the exact d=0 bias).
// *** R5 configuration, verbatim — best measured (gemm 95.5 us / 645 TF). ***
// BM=BN=128, BK=64, 256 thr (2x2 waves, wave tile 64x64), grid 1024 ->
// 4 blocks/CU. Plain 2-barrier K-loop. All measured variants regressed:
//   R6 256x128/512thr (2 blk/CU), R7 dbuf 1-barrier, R8 2-wave blocks,
//   R9 runtime-rotated epilogue (dynamic acc index -> SCRATCH SPILL: 1.9 GB
//   writes, MfmaUtil 0.5%. Never index per-thread arrays with runtime values.)
// XCD mapping: bidx&7 = m-tile mod 8; all 4 K-chunks of a tile share an XCD
// (atomics resolve in one L2).
// LDS swizzle: row r stores logical k-chunk s at slot s ^ (r & 7) -> every
// ds_read_b128 covers banks uniformly (0 conflicts, R4-R5 measured).
// ---------------------------------------------------------------------------
#define BM 128
#define BN 128
#define BK 64
#define KSPLIT 4
#define KCH (KD2 / KSPLIT)   // 1792 -> 28 iters of BK=64

__global__ __launch_bounds__(256, 4) void gemm_kernel(
    const unsigned short* __restrict__ A,    // bf16 bits [BATCH][KD2]
    const unsigned short* __restrict__ Bt,   // bf16 bits [OUT_DIM][KD2]
    const float* __restrict__ bias_part,     // [32][OUT_DIM]
    float* __restrict__ C) {                 // [BATCH][OUT_DIM], pre-zeroed
    __shared__ __align__(16) unsigned short lA[BM * BK];  // 16 KB
    __shared__ __align__(16) unsigned short lB[BN * BK];  // 16 KB

    const int tid  = threadIdx.x;
    const int bidx = blockIdx.x;
    const int m0 = (((bidx >> 3) & 3) * 8 + (bidx & 7)) * BM;  // low3 -> XCD
    const int n0 = ((bidx >> 5) & 7) * BN;
    const int ch = bidx >> 8;
    const size_t kb = (size_t)ch * KCH;

    const int lane  = tid & 63;
    const int wid   = tid >> 6;
    const int wm    = (wid & 1) * 64;
    const int wn    = (wid >> 1) * 64;
    const int row16 = lane & 15;
    const int quad  = lane >> 4;

    // ds_read element offsets for kk=0; kk=1 is ^32 elems (slot ^4).
    int aOff[4], bOff[4];
#pragma unroll
    for (int mt = 0; mt < 4; ++mt) {
        int r = wm + mt * 16 + row16;
        aOff[mt] = r * BK + ((quad ^ (r & 7)) * 8);
    }
#pragma unroll
    for (int nt = 0; nt < 4; ++nt) {
        int c = wn + nt * 16 + row16;
        bOff[nt] = c * BK + ((quad ^ (c & 7)) * 8);
    }

    // Staging: tile = 1024 x 16B chunks; thread t -> chunks t + 256*j.
    // Phys chunk c: row r = c>>3, slot s = c&7, global k-chunk = s ^ (r&7).
    // c+256 -> r+32 (r&7 unchanged -> same swizzle term), +32*KD2 elems.
    const int r0 = tid >> 3, s0 = tid & 7;
    const unsigned short* gA0 = A  + (size_t)(m0 + r0) * KD2 + kb + ((s0 ^ (r0 & 7)) * 8);
    const unsigned short* gB0 = Bt + (size_t)(n0 + r0) * KD2 + kb + ((s0 ^ (r0 & 7)) * 8);
    unsigned short* dA = lA + tid * 8;
    unsigned short* dB = lB + tid * 8;

    f32x4 acc[4][4] = {};

    for (int k0 = 0; k0 < KCH; k0 += BK) {
#pragma unroll
        for (int j = 0; j < 4; ++j)
            ld_lds16(gA0 + k0 + (size_t)j * 32 * KD2, dA + j * 2048);
#pragma unroll
        for (int j = 0; j < 4; ++j)
            ld_lds16(gB0 + k0 + (size_t)j * 32 * KD2, dB + j * 2048);
        __syncthreads();

#pragma unroll
        for (int kk = 0; kk < 2; ++kk) {
            const int xo = kk * 32;
            bf16x8 aF[4], bF[4];
#pragma unroll
            for (int mt = 0; mt < 4; ++mt) aF[mt] = *(const bf16x8*)(lA + (aOff[mt] ^ xo));
#pragma unroll
            for (int nt = 0; nt < 4; ++nt) bF[nt] = *(const bf16x8*)(lB + (bOff[nt] ^ xo));
#pragma unroll
            for (int mt = 0; mt < 4; ++mt)
#pragma unroll
                for (int nt = 0; nt < 4; ++nt)
                    acc[mt][nt] = __builtin_amdgcn_mfma_f32_16x16x32_bf16(
                        aF[mt], bF[nt], acc[mt][nt], 0, 0, 0);
        }
        __syncthreads();
    }

    // ch==0 blocks fold in the exact d=0 bias.
    if (ch == 0) {
        float* sb = (float*)lA;   // safe: loop ended with __syncthreads
        if (tid < BN) {
            float s = 0.f;
#pragma unroll
            for (int g = 0; g < 32; ++g) s += bias_part[(size_t)g * OUT_DIM + n0 + tid];
            sb[tid] = s;
        }
        __syncthreads();
    }
    const float* sb = (const float*)lA;

    // C/D layout (m89-verified): col = lane&15, row = quad*4 + reg.
    // STATIC loop order only — runtime indexing of acc spills it to scratch.
#pragma unroll
    for (int mt = 0; mt < 4; ++mt) {
        const int rbase = m0 + wm + mt * 16 + quad * 4;
#pragma unroll
        for (int nt = 0; nt < 4; ++nt) {
            const int col = n0 + wn + nt * 16 + row16;
            const float bv = (ch == 0) ? sb[wn + nt * 16 + row16] : 0.f;
#pragma unroll
            for (int r = 0; r < 4; ++r)
                atomicAdd(&C[(size_t)(rbase + r) * OUT_DIM + col], acc[mt][nt][r] + bv);
        }
    }
}

// ---------------------------------------------------------------------------
// Fallback (only if ws too small): fp32, block per batch row, basis in LDS.
// ---------------------------------------------------------------------------
__global__ __launch_bounds__(256) void fallback_kernel(
    const float* __restrict__ x, const float* __restrict__ ap,
    const float* __restrict__ qp, const float* __restrict__ coeffs,
    float* __restrict__ out) {
    __shared__ float sb[IN_DIM][NB];   // 32 KB
    const int b = blockIdx.x;
    const float a = ap[0], q = qp[0];
    for (int i = threadIdx.x; i < IN_DIM; i += 256) {
        float xt = fast_tanh(x[(size_t)b * IN_DIM + i]);
        float p0 = 1.0f, p1 = xt - a;
        sb[i][0] = p0; sb[i][1] = p1;
        float qn = q, qn1 = 1.0f;
#pragma unroll
        for (int n = 2; n < NB; ++n) {
            qn *= q; qn1 *= q;
            float p2 = (xt - (a + qn)) * p1 - a * qn1 * p0;
            sb[i][n] = p2;
            p0 = p1; p1 = p2;
        }
    }
    __syncthreads();
    float acc[4] = {0.f, 0.f, 0.f, 0.f};
    for (int i = 0; i < IN_DIM; ++i) {
        float bb[NB];
#pragma unroll
        for (int d = 0; d < NB; ++d) bb[d] = sb[i][d];
#pragma unroll
        for (int j = 0; j < 4; ++j) {
            int o = threadIdx.x + j * 256;
            const float* cf = coeffs + ((size_t)i * OUT_DIM + o) * NB;
            float s = 0.f;
#pragma unroll
            for (int d = 0; d < NB; ++d) s += bb[d] * cf[d];
            acc[j] += s;
        }
    }
#pragma unroll
    for (int j = 0; j < 4; ++j)
        out[(size_t)b * OUT_DIM + threadIdx.x + j * 256] = acc[j];
}

// ---------------------------------------------------------------------------
extern "C" void kernel_launch(void* const* d_in, const int* in_sizes, int n_in,
                              void* d_out, int out_size, void* d_ws, size_t ws_size,
                              hipStream_t stream) {
    const float* x      = (const float*)d_in[0];
    const float* a      = (const float*)d_in[1];
    const float* q      = (const float*)d_in[2];
    const float* coeffs = (const float*)d_in[3];
    float* out = (float*)d_out;

    const size_t needA = (size_t)BATCH * KD2 * sizeof(unsigned short);   // 56 MB
    const size_t needB = (size_t)OUT_DIM * KD2 * sizeof(unsigned short); // 14 MB
    const size_t needBias = 32 * (size_t)OUT_DIM * sizeof(float);        // 128 KB

    if (ws_size >= needA + needB + needBias) {
        unsigned short* Aw = (unsigned short*)d_ws;
        unsigned short* Bt = Aw + (size_t)BATCH * KD2;
        float* bias_part = (float*)((char*)d_ws + needA + needB);
        prep_and_repack<<<PREP_BLOCKS + REPACK_BLOCKS + ZERO_BLOCKS, 256, 0, stream>>>(
            x, a, q, coeffs, Aw, Bt, bias_part, out);
        gemm_kernel<<<(BATCH / BM) * (OUT_DIM / BN) * KSPLIT, 256, 0, stream>>>(
            Aw, Bt, bias_part, out);
    } else {
        fallback_kernel<<<BATCH, 256, 0, stream>>>(x, a, q, coeffs, out);
    }
}